// Round 1
// baseline (164.934 us; speedup 1.0000x reference)
//
#include <hip/hip_runtime.h>

#define NQ 10
#define NL 5

struct cplx { float re, im; };

__device__ __forceinline__ cplx cmul(cplx a, cplx b) {
    return { a.re * b.re - a.im * b.im, a.re * b.im + a.im * b.re };
}
__device__ __forceinline__ cplx cadd(cplx a, cplx b) { return { a.re + b.re, a.im + b.im }; }

// Apply 2x2 gate on bit position P (0 = LSB of the 10-bit index).
// Lane owns 16 amplitudes: k = lane*16 + r. P<4 -> in-register; P>=4 -> cross-lane shuffle.
template <int P>
__device__ __forceinline__ void apply_gate(cplx a[16], cplx u00, cplx u01, cplx u10, cplx u11,
                                           int lane) {
    if constexpr (P < 4) {
        constexpr int LOW = 1 << P;
#pragma unroll
        for (int base = 0; base < 16; ++base) {
            if (base & LOW) continue;
            cplx a0 = a[base], a1 = a[base | LOW];
            a[base]       = cadd(cmul(u00, a0), cmul(u01, a1));
            a[base | LOW] = cadd(cmul(u10, a0), cmul(u11, a1));
        }
    } else {
        constexpr int M = 1 << (P - 4);
        const int bit = (lane >> (P - 4)) & 1;
        const cplx ua = bit ? u10 : u00;
        const cplx ub = bit ? u11 : u01;
#pragma unroll
        for (int r = 0; r < 16; ++r) {
            cplx o;
            o.re = __shfl_xor(a[r].re, M, 64);
            o.im = __shfl_xor(a[r].im, M, 64);
            cplx lo = bit ? o : a[r];   // amplitude with bit=0
            cplx hi = bit ? a[r] : o;   // amplitude with bit=1
            a[r] = cadd(cmul(ua, lo), cmul(ub, hi));
        }
    }
}

// wire q (PennyLane: wire 0 = MSB) -> bit position 9-q
__device__ __forceinline__ void apply_q(cplx a[16], cplx u00, cplx u01, cplx u10, cplx u11,
                                        int q, int lane) {
    switch (q) {
        case 0: apply_gate<9>(a, u00, u01, u10, u11, lane); break;
        case 1: apply_gate<8>(a, u00, u01, u10, u11, lane); break;
        case 2: apply_gate<7>(a, u00, u01, u10, u11, lane); break;
        case 3: apply_gate<6>(a, u00, u01, u10, u11, lane); break;
        case 4: apply_gate<5>(a, u00, u01, u10, u11, lane); break;
        case 5: apply_gate<4>(a, u00, u01, u10, u11, lane); break;
        case 6: apply_gate<3>(a, u00, u01, u10, u11, lane); break;
        case 7: apply_gate<2>(a, u00, u01, u10, u11, lane); break;
        case 8: apply_gate<1>(a, u00, u01, u10, u11, lane); break;
        case 9: apply_gate<0>(a, u00, u01, u10, u11, lane); break;
    }
}

// U = Rz(tz) @ Ry(ty) @ Rx(tx)
__device__ __forceinline__ void var_layer(cplx a[16], const float* __restrict__ th, int lane) {
#pragma unroll
    for (int q = 0; q < NQ; ++q) {
        float tx = th[q * 3 + 0], ty = th[q * 3 + 1], tz = th[q * 3 + 2];
        float cx, sx, cy, sy, cz, sz;
        __sincosf(0.5f * tx, &sx, &cx);
        __sincosf(0.5f * ty, &sy, &cy);
        __sincosf(0.5f * tz, &sz, &cz);
        // derived: U00 = (cz - i sz)(cy cx + i sy sx), U11 = conj(U00)
        //          U10 = (cz + i sz)(sy cx - i cy sx), U01 = -conj(U10)
        cplx u00 = {  cz * cy * cx + sz * sy * sx,  cz * sy * sx - sz * cy * cx };
        cplx u01 = { -cz * sy * cx - sz * cy * sx,  sz * sy * cx - cz * cy * sx };
        cplx u10 = {  cz * sy * cx + sz * cy * sx,  sz * sy * cx - cz * cy * sx };
        cplx u11 = {  cz * cy * cx + sz * sy * sx,  sz * cy * cx - cz * sy * sx };
        apply_q(a, u00, u01, u10, u11, q, lane);
    }
}

__device__ __forceinline__ void enc_layer(cplx a[16], const float* xr, const float* __restrict__ lm,
                                          int lane) {
#pragma unroll
    for (int q = 0; q < NQ; ++q) {
        float t = xr[q] * lm[q];
        float c, s;
        __sincosf(0.5f * t, &s, &c);
        cplx u00 = { c, 0.f }, u01 = { 0.f, -s }, u10 = { 0.f, -s }, u11 = { c, 0.f };
        apply_q(a, u00, u01, u10, u11, q, lane);
    }
}

__device__ __forceinline__ void apply_diag_signs(cplx a[16], unsigned mask) {
#pragma unroll
    for (int r = 0; r < 16; ++r) {
        unsigned s = ((mask >> r) & 1u) << 31;
        a[r].re = __uint_as_float(__float_as_uint(a[r].re) ^ s);
        a[r].im = __uint_as_float(__float_as_uint(a[r].im) ^ s);
    }
}

__global__ void __launch_bounds__(256) pqc_kernel(const float* __restrict__ x,
                                                  const float* __restrict__ theta,
                                                  const float* __restrict__ lam,
                                                  const float* __restrict__ w,
                                                  float* __restrict__ out, int B) {
    const int lane = threadIdx.x & 63;
    const int b = blockIdx.x * (blockDim.x >> 6) + (threadIdx.x >> 6);
    if (b >= B) return;

    cplx a[16];
#pragma unroll
    for (int r = 0; r < 16; ++r) a[r] = { 0.f, 0.f };
    if (lane == 0) a[0].re = 1.f;

    // CZ-ring sign mask and Z^n sign mask for this lane's 16 amplitudes.
    // CZ ring over wires (i,i+1 mod 10) == bit pairs (p,p+1) p=0..8 plus (0,9).
    unsigned czmask = 0, zmask = 0;
#pragma unroll
    for (int r = 0; r < 16; ++r) {
        int k = (lane << 4) | r;
        int par = __popc(k & (k >> 1)) + ((k & (k >> 9)) & 1);
        czmask |= (unsigned)(par & 1) << r;
        zmask  |= (unsigned)(__popc(k) & 1) << r;
    }

    float xr[NQ];
#pragma unroll
    for (int q = 0; q < NQ; ++q) xr[q] = x[b * NQ + q];

    for (int l = 0; l < NL; ++l) {
        var_layer(a, theta + l * NQ * 3, lane);
        apply_diag_signs(a, czmask);
        enc_layer(a, xr, lam + l * NQ, lane);
    }
    var_layer(a, theta + NL * NQ * 3, lane);
    apply_diag_signs(a, czmask);

    // <Z x ... x Z> = sum |amp|^2 * (-1)^popcount(k)
    float ez = 0.f;
#pragma unroll
    for (int r = 0; r < 16; ++r) {
        float p = a[r].re * a[r].re + a[r].im * a[r].im;
        ez += ((zmask >> r) & 1u) ? -p : p;
    }
#pragma unroll
    for (int off = 32; off > 0; off >>= 1) ez += __shfl_xor(ez, off, 64);

    if (lane == 0) {
        float l0 = ez * w[0], l1 = ez * w[1];   // BETA = 1
        float m = fmaxf(l0, l1);
        float e0 = __expf(l0 - m), e1 = __expf(l1 - m);
        float inv = 1.f / (e0 + e1);
        out[2 * b + 0] = e0 * inv;
        out[2 * b + 1] = e1 * inv;
    }
}

extern "C" void kernel_launch(void* const* d_in, const int* in_sizes, int n_in,
                              void* d_out, int out_size, void* d_ws, size_t ws_size,
                              hipStream_t stream) {
    const float* x     = (const float*)d_in[0];
    const float* theta = (const float*)d_in[1];
    const float* lam   = (const float*)d_in[2];
    const float* w     = (const float*)d_in[3];
    float* out = (float*)d_out;

    const int B = in_sizes[0] / NQ;            // 2048
    const int wavesPerBlock = 256 / 64;        // 4
    const int blocks = (B + wavesPerBlock - 1) / wavesPerBlock;
    hipLaunchKernelGGL(pqc_kernel, dim3(blocks), dim3(256), 0, stream,
                       x, theta, lam, w, out, B);
}

// Round 2
// 114.818 us; speedup vs baseline: 1.4365x; 1.4365x over previous
//
#include <hip/hip_runtime.h>

#define NQ 10
#define NL 5

struct cplx { float re, im; };

// Apply 2x2 gate on bit position P (0 = LSB of the 10-bit index).
// Lane owns 16 amplitudes: k = lane*16 + r. P<4 -> in-register; P>=4 -> cross-lane shuffle.
template <int P>
__device__ __forceinline__ void apply_gate(cplx a[16], cplx u00, cplx u01, cplx u10, cplx u11,
                                           int lane) {
    if constexpr (P < 4) {
        constexpr int LOW = 1 << P;
#pragma unroll
        for (int base = 0; base < 16; ++base) {
            if (base & LOW) continue;
            cplx a0 = a[base], a1 = a[base | LOW];
            a[base].re       = u00.re * a0.re - u00.im * a0.im + u01.re * a1.re - u01.im * a1.im;
            a[base].im       = u00.re * a0.im + u00.im * a0.re + u01.re * a1.im + u01.im * a1.re;
            a[base | LOW].re = u10.re * a0.re - u10.im * a0.im + u11.re * a1.re - u11.im * a1.im;
            a[base | LOW].im = u10.re * a0.im + u10.im * a0.re + u11.re * a1.im + u11.im * a1.re;
        }
    } else {
        constexpr int M = 1 << (P - 4);
        const int bit = (lane >> (P - 4)) & 1;
        // p multiplies own amplitude, q multiplies the shuffled partner — no per-r selects.
        const cplx p = bit ? u11 : u00;
        const cplx q = bit ? u10 : u01;
#pragma unroll
        for (int r = 0; r < 16; ++r) {
            cplx o;
            o.re = __shfl_xor(a[r].re, M, 64);
            o.im = __shfl_xor(a[r].im, M, 64);
            float nr = p.re * a[r].re - p.im * a[r].im + q.re * o.re - q.im * o.im;
            float ni = p.re * a[r].im + p.im * a[r].re + q.re * o.im + q.im * o.re;
            a[r].re = nr;
            a[r].im = ni;
        }
    }
}

// wire q (PennyLane: wire 0 = MSB) -> bit position 9-q
__device__ __forceinline__ void apply_q(cplx a[16], cplx u00, cplx u01, cplx u10, cplx u11,
                                        int q, int lane) {
    switch (q) {
        case 0: apply_gate<9>(a, u00, u01, u10, u11, lane); break;
        case 1: apply_gate<8>(a, u00, u01, u10, u11, lane); break;
        case 2: apply_gate<7>(a, u00, u01, u10, u11, lane); break;
        case 3: apply_gate<6>(a, u00, u01, u10, u11, lane); break;
        case 4: apply_gate<5>(a, u00, u01, u10, u11, lane); break;
        case 5: apply_gate<4>(a, u00, u01, u10, u11, lane); break;
        case 6: apply_gate<3>(a, u00, u01, u10, u11, lane); break;
        case 7: apply_gate<2>(a, u00, u01, u10, u11, lane); break;
        case 8: apply_gate<1>(a, u00, u01, u10, u11, lane); break;
        case 9: apply_gate<0>(a, u00, u01, u10, u11, lane); break;
    }
}

// U = Rz(tz) @ Ry(ty) @ Rx(tx)  (SU(2): u11 = conj(u00), u10 = -conj(u01))
__device__ __forceinline__ void make_u(float tx, float ty, float tz,
                                       cplx& u00, cplx& u01, cplx& u10, cplx& u11) {
    float cx, sx, cy, sy, cz, sz;
    __sincosf(0.5f * tx, &sx, &cx);
    __sincosf(0.5f * ty, &sy, &cy);
    __sincosf(0.5f * tz, &sz, &cz);
    u00 = {  cz * cy * cx + sz * sy * sx,  cz * sy * sx - sz * cy * cx };
    u01 = { -cz * sy * cx - sz * cy * sx,  sz * sy * cx - cz * cy * sx };
    u10 = { -u01.re, u01.im };
    u11 = {  u00.re, -u00.im };
}

__device__ __forceinline__ void apply_diag_signs(cplx a[16], unsigned mask) {
#pragma unroll
    for (int r = 0; r < 16; ++r) {
        unsigned s = ((mask >> r) & 1u) << 31;
        a[r].re = __uint_as_float(__float_as_uint(a[r].re) ^ s);
        a[r].im = __uint_as_float(__float_as_uint(a[r].im) ^ s);
    }
}

__global__ void __launch_bounds__(256) pqc_kernel(const float* __restrict__ x,
                                                  const float* __restrict__ theta,
                                                  const float* __restrict__ lam,
                                                  const float* __restrict__ w,
                                                  float* __restrict__ out, int B) {
    const int lane = threadIdx.x & 63;
    const int b = blockIdx.x * (blockDim.x >> 6) + (threadIdx.x >> 6);
    if (b >= B) return;

    cplx a[16];
#pragma unroll
    for (int r = 0; r < 16; ++r) a[r] = { 0.f, 0.f };
    if (lane == 0) a[0].re = 1.f;

    // CZ-ring sign mask and Z^n sign mask for this lane's 16 amplitudes.
    unsigned czmask = 0, zmask = 0;
#pragma unroll
    for (int r = 0; r < 16; ++r) {
        int k = (lane << 4) | r;
        int par = __popc(k & (k >> 1)) + ((k & (k >> 9)) & 1);
        czmask |= (unsigned)(par & 1) << r;
        zmask  |= (unsigned)(__popc(k) & 1) << r;
    }

    float xr[NQ];
#pragma unroll
    for (int q = 0; q < NQ; ++q) xr[q] = x[b * NQ + q];

    // Layer 0 variational gates (unfused).
#pragma unroll
    for (int q = 0; q < NQ; ++q) {
        cplx u00, u01, u10, u11;
        make_u(theta[q * 3 + 0], theta[q * 3 + 1], theta[q * 3 + 2], u00, u01, u10, u11);
        apply_q(a, u00, u01, u10, u11, q, lane);
    }
    apply_diag_signs(a, czmask);

    // Layers 1..NL: fused W = U_theta(l) * RX(x*lam(l-1)) per qubit, then CZ ring.
    for (int l = 1; l <= NL; ++l) {
        const float* th = theta + l * NQ * 3;
        const float* lm = lam + (l - 1) * NQ;
#pragma unroll
        for (int q = 0; q < NQ; ++q) {
            cplx u00, u01, u10, u11;
            make_u(th[q * 3 + 0], th[q * 3 + 1], th[q * 3 + 2], u00, u01, u10, u11);
            float t = xr[q] * lm[q];
            float c, s;
            __sincosf(0.5f * t, &s, &c);
            // W = U * RX(t), RX = [[c, -is], [-is, c]]
            cplx w00 = { c * u00.re + s * u01.im,  c * u00.im - s * u01.re };
            cplx w01 = { s * u00.im + c * u01.re, -s * u00.re + c * u01.im };
            cplx w10 = { c * u10.re + s * u11.im,  c * u10.im - s * u11.re };
            cplx w11 = { s * u10.im + c * u11.re, -s * u10.re + c * u11.im };
            apply_q(a, w00, w01, w10, w11, q, lane);
        }
        apply_diag_signs(a, czmask);
    }

    // <Z x ... x Z> = sum |amp|^2 * (-1)^popcount(k)
    float ez = 0.f;
#pragma unroll
    for (int r = 0; r < 16; ++r) {
        float p = a[r].re * a[r].re + a[r].im * a[r].im;
        ez += ((zmask >> r) & 1u) ? -p : p;
    }
#pragma unroll
    for (int off = 32; off > 0; off >>= 1) ez += __shfl_xor(ez, off, 64);

    if (lane == 0) {
        float l0 = ez * w[0], l1 = ez * w[1];   // BETA = 1
        float m = fmaxf(l0, l1);
        float e0 = __expf(l0 - m), e1 = __expf(l1 - m);
        float inv = 1.f / (e0 + e1);
        out[2 * b + 0] = e0 * inv;
        out[2 * b + 1] = e1 * inv;
    }
}

extern "C" void kernel_launch(void* const* d_in, const int* in_sizes, int n_in,
                              void* d_out, int out_size, void* d_ws, size_t ws_size,
                              hipStream_t stream) {
    const float* x     = (const float*)d_in[0];
    const float* theta = (const float*)d_in[1];
    const float* lam   = (const float*)d_in[2];
    const float* w     = (const float*)d_in[3];
    float* out = (float*)d_out;

    const int B = in_sizes[0] / NQ;            // 2048
    const int wavesPerBlock = 256 / 64;        // 4
    const int blocks = (B + wavesPerBlock - 1) / wavesPerBlock;
    hipLaunchKernelGGL(pqc_kernel, dim3(blocks), dim3(256), 0, stream,
                       x, theta, lam, w, out, B);
}

// Round 3
// 95.665 us; speedup vs baseline: 1.7241x; 1.2002x over previous
//
#include <hip/hip_runtime.h>

#define NQ 10
#define NL 5

typedef float v2f __attribute__((ext_vector_type(2)));

__device__ __forceinline__ v2f sp(float s) { v2f r = { s, s }; return r; }

// U = Rz(tz) @ Ry(ty) @ Rx(tx)  (SU(2): u11 = conj(u00), u10 = -conj(u01))
__device__ __forceinline__ void make_u(float tx, float ty, float tz,
                                       float& u00r, float& u00i, float& u01r, float& u01i,
                                       float& u10r, float& u10i, float& u11r, float& u11i) {
    float cx, sx, cy, sy, cz, sz;
    __sincosf(0.5f * tx, &sx, &cx);
    __sincosf(0.5f * ty, &sy, &cy);
    __sincosf(0.5f * tz, &sz, &cz);
    u00r =  cz * cy * cx + sz * sy * sx;
    u00i =  cz * sy * sx - sz * cy * cx;
    u01r = -cz * sy * cx - sz * cy * sx;
    u01i =  sz * sy * cx - cz * cy * sx;
    u10r = -u01r;  u10i =  u01i;
    u11r =  u00r;  u11i = -u00i;
}

// Setup: 60 gate matrices (6 layers x 10 qubits), batch-independent.
// gm[g*16 + 0..7]  = V0 = U  (u00r,u00i,u01r,u01i,u10r,u10i,u11r,u11i)
// gm[g*16 + 8..15] = V1 = -i * [[u01,u00],[u11,u10]]   (used for l>=1 fusion W = c*V0 + s*V1)
__global__ void pqc_setup(const float* __restrict__ theta, float* __restrict__ gm) {
    int g = threadIdx.x;
    if (g >= (NL + 1) * NQ) return;
    const float* th = theta + g * 3;
    float u00r, u00i, u01r, u01i, u10r, u10i, u11r, u11i;
    make_u(th[0], th[1], th[2], u00r, u00i, u01r, u01i, u10r, u10i, u11r, u11i);
    float* o = gm + g * 16;
    o[0] = u00r;  o[1] = u00i;  o[2] = u01r;  o[3] = u01i;
    o[4] = u10r;  o[5] = u10i;  o[6] = u11r;  o[7] = u11i;
    o[8]  = u01i; o[9]  = -u01r; o[10] = u00i; o[11] = -u00r;
    o[12] = u11i; o[13] = -u11r; o[14] = u10i; o[15] = -u10r;
}

// State: amplitude k = lane*16 + r, r = 2*j + h.  fr[j]/fi[j] hold re/im of (r=2j, r=2j+1).
// Bit position P of k: P=0 -> h (inside v2f), P=1..3 -> j bits, P=4..9 -> lane bits.
template <int P>
__device__ __forceinline__ void apply_p(v2f fr[8], v2f fi[8],
                                        float w00r, float w00i, float w01r, float w01i,
                                        float w10r, float w10i, float w11r, float w11i,
                                        int lane) {
    if constexpr (P == 0) {
        v2f c0r = { w00r, w11r }, c0i = { w00i, w11i };
        v2f c1r = { w01r, w10r }, c1i = { w01i, w10i };
#pragma unroll
        for (int j = 0; j < 8; ++j) {
            v2f ar = fr[j], ai = fi[j];
            v2f srp = ar.yx, sip = ai.yx;
            fr[j] = c0r * ar - c0i * ai + c1r * srp - c1i * sip;
            fi[j] = c0r * ai + c0i * ar + c1r * sip + c1i * srp;
        }
    } else if constexpr (P < 4) {
        constexpr int LJ = 1 << (P - 1);
        v2f a00r = sp(w00r), a00i = sp(w00i), a01r = sp(w01r), a01i = sp(w01i);
        v2f a10r = sp(w10r), a10i = sp(w10i), a11r = sp(w11r), a11i = sp(w11i);
#pragma unroll
        for (int base = 0; base < 8; ++base) {
            if (base & LJ) continue;
            v2f a0r = fr[base], a0i = fi[base];
            v2f a1r = fr[base | LJ], a1i = fi[base | LJ];
            fr[base]      = a00r * a0r - a00i * a0i + a01r * a1r - a01i * a1i;
            fi[base]      = a00r * a0i + a00i * a0r + a01r * a1i + a01i * a1r;
            fr[base | LJ] = a10r * a0r - a10i * a0i + a11r * a1r - a11i * a1i;
            fi[base | LJ] = a10r * a0i + a10i * a0r + a11r * a1i + a11i * a1r;
        }
    } else {
        constexpr int M = 1 << (P - 4);
        const int bit = (lane >> (P - 4)) & 1;
        v2f pr = sp(bit ? w11r : w00r), pi = sp(bit ? w11i : w00i);
        v2f qr = sp(bit ? w10r : w01r), qi = sp(bit ? w10i : w01i);
#pragma unroll
        for (int j = 0; j < 8; ++j) {
            v2f ofr, ofi;
            ofr.x = __shfl_xor(fr[j].x, M, 64);
            ofr.y = __shfl_xor(fr[j].y, M, 64);
            ofi.x = __shfl_xor(fi[j].x, M, 64);
            ofi.y = __shfl_xor(fi[j].y, M, 64);
            v2f nr = pr * fr[j] - pi * fi[j] + qr * ofr - qi * ofi;
            v2f ni = pr * fi[j] + pi * fr[j] + qr * ofi + qi * ofr;
            fr[j] = nr;
            fi[j] = ni;
        }
    }
}

// wire q (PennyLane: wire 0 = MSB) -> bit position 9-q
__device__ __forceinline__ void apply_q(v2f fr[8], v2f fi[8],
                                        float w00r, float w00i, float w01r, float w01i,
                                        float w10r, float w10i, float w11r, float w11i,
                                        int q, int lane) {
    switch (q) {
        case 0: apply_p<9>(fr, fi, w00r, w00i, w01r, w01i, w10r, w10i, w11r, w11i, lane); break;
        case 1: apply_p<8>(fr, fi, w00r, w00i, w01r, w01i, w10r, w10i, w11r, w11i, lane); break;
        case 2: apply_p<7>(fr, fi, w00r, w00i, w01r, w01i, w10r, w10i, w11r, w11i, lane); break;
        case 3: apply_p<6>(fr, fi, w00r, w00i, w01r, w01i, w10r, w10i, w11r, w11i, lane); break;
        case 4: apply_p<5>(fr, fi, w00r, w00i, w01r, w01i, w10r, w10i, w11r, w11i, lane); break;
        case 5: apply_p<4>(fr, fi, w00r, w00i, w01r, w01i, w10r, w10i, w11r, w11i, lane); break;
        case 6: apply_p<3>(fr, fi, w00r, w00i, w01r, w01i, w10r, w10i, w11r, w11i, lane); break;
        case 7: apply_p<2>(fr, fi, w00r, w00i, w01r, w01i, w10r, w10i, w11r, w11i, lane); break;
        case 8: apply_p<1>(fr, fi, w00r, w00i, w01r, w01i, w10r, w10i, w11r, w11i, lane); break;
        case 9: apply_p<0>(fr, fi, w00r, w00i, w01r, w01i, w10r, w10i, w11r, w11i, lane); break;
    }
}

__global__ void __launch_bounds__(256) pqc_kernel(const float* __restrict__ x,
                                                  const float* __restrict__ lam,
                                                  const float* __restrict__ w,
                                                  const float* __restrict__ gm,
                                                  float* __restrict__ out, int B) {
    const int lane = threadIdx.x & 63;
    const int b = blockIdx.x * (blockDim.x >> 6) + (threadIdx.x >> 6);
    if (b >= B) return;
    const int bu = __builtin_amdgcn_readfirstlane(b);   // wave-uniform -> scalar loads for x

    v2f fr[8], fi[8];
#pragma unroll
    for (int j = 0; j < 8; ++j) { fr[j] = sp(0.f); fi[j] = sp(0.f); }
    if (lane == 0) fr[0].x = 1.f;

    // CZ-ring and Z^n sign vectors (+-1 per amplitude).
    v2f sv[8];
    unsigned zmask = 0;
#pragma unroll
    for (int j = 0; j < 8; ++j) {
#pragma unroll
        for (int h = 0; h < 2; ++h) {
            int k = (lane << 4) | (2 * j + h);
            int par = (__popc(k & (k >> 1)) + ((k & (k >> 9)) & 1)) & 1;
            float s = __uint_as_float(0x3f800000u | ((unsigned)par << 31));
            if (h == 0) sv[j].x = s; else sv[j].y = s;
            zmask |= (unsigned)(__popc(k) & 1) << (2 * j + h);
        }
    }

    float xr[NQ];
#pragma unroll
    for (int q = 0; q < NQ; ++q) xr[q] = x[bu * NQ + q];

    // Layer 0: variational gates straight from precomputed V0.
#pragma unroll
    for (int q = 0; q < NQ; ++q) {
        const float* g = gm + q * 16;
        apply_q(fr, fi, g[0], g[1], g[2], g[3], g[4], g[5], g[6], g[7], q, lane);
    }
#pragma unroll
    for (int j = 0; j < 8; ++j) { fr[j] *= sv[j]; fi[j] *= sv[j]; }

    // Layers 1..NL: W = c*V0 + s*V1 (fused U_theta(l) * RX(x*lam(l-1))), then CZ ring.
#pragma unroll
    for (int l = 1; l <= NL; ++l) {
        const float* lm = lam + (l - 1) * NQ;
#pragma unroll
        for (int q = 0; q < NQ; ++q) {
            const float* g = gm + (l * NQ + q) * 16;
            float t = xr[q] * lm[q];
            float c, s;
            __sincosf(0.5f * t, &s, &c);
            float w00r = c * g[0] + s * g[8],  w00i = c * g[1] + s * g[9];
            float w01r = c * g[2] + s * g[10], w01i = c * g[3] + s * g[11];
            float w10r = c * g[4] + s * g[12], w10i = c * g[5] + s * g[13];
            float w11r = c * g[6] + s * g[14], w11i = c * g[7] + s * g[15];
            apply_q(fr, fi, w00r, w00i, w01r, w01i, w10r, w10i, w11r, w11i, q, lane);
        }
#pragma unroll
        for (int j = 0; j < 8; ++j) { fr[j] *= sv[j]; fi[j] *= sv[j]; }
    }

    // <Z^n> = sum |amp|^2 * (-1)^popcount(k)
    v2f acc = sp(0.f);
#pragma unroll
    for (int j = 0; j < 8; ++j) {
        v2f zs;
        zs.x = __uint_as_float(0x3f800000u | (((zmask >> (2 * j)) & 1u) << 31));
        zs.y = __uint_as_float(0x3f800000u | (((zmask >> (2 * j + 1)) & 1u) << 31));
        acc += zs * (fr[j] * fr[j] + fi[j] * fi[j]);
    }
    float ez = acc.x + acc.y;
#pragma unroll
    for (int off = 32; off > 0; off >>= 1) ez += __shfl_xor(ez, off, 64);

    if (lane == 0) {
        float l0 = ez * w[0], l1 = ez * w[1];   // BETA = 1
        float m = fmaxf(l0, l1);
        float e0 = __expf(l0 - m), e1 = __expf(l1 - m);
        float inv = 1.f / (e0 + e1);
        out[2 * b + 0] = e0 * inv;
        out[2 * b + 1] = e1 * inv;
    }
}

extern "C" void kernel_launch(void* const* d_in, const int* in_sizes, int n_in,
                              void* d_out, int out_size, void* d_ws, size_t ws_size,
                              hipStream_t stream) {
    const float* x     = (const float*)d_in[0];
    const float* theta = (const float*)d_in[1];
    const float* lam   = (const float*)d_in[2];
    const float* w     = (const float*)d_in[3];
    float* out = (float*)d_out;
    float* gm  = (float*)d_ws;                 // 60 gates * 16 floats = 3840 B

    const int B = in_sizes[0] / NQ;            // 2048
    hipLaunchKernelGGL(pqc_setup, dim3(1), dim3(64), 0, stream, theta, gm);

    const int wavesPerBlock = 256 / 64;        // 4
    const int blocks = (B + wavesPerBlock - 1) / wavesPerBlock;
    hipLaunchKernelGGL(pqc_kernel, dim3(blocks), dim3(256), 0, stream,
                       x, lam, w, gm, out, B);
}

// Round 5
// 91.850 us; speedup vs baseline: 1.7957x; 1.0415x over previous
//
#include <hip/hip_runtime.h>

#define NQ 10
#define NL 5

typedef float v2f __attribute__((ext_vector_type(2)));

__device__ __forceinline__ v2f sp(float s) { v2f r = { s, s }; return r; }

// ---- cross-lane xor exchange, mask-specialized onto the cheapest pipe ----
// xor 1,2,8: DPP (VALU, ~2cyc). xor 16,32: permlane*_swap (VALU) on gfx950.
// xor 4: ds_swizzle (only remaining DS-pipe op).
template <int M>
__device__ __forceinline__ float lane_xor(float v, int lane) {
    unsigned u = __float_as_uint(v);
    if constexpr (M == 1) {        // quad_perm [1,0,3,2]
        return __uint_as_float((unsigned)__builtin_amdgcn_update_dpp(0, (int)u, 0xB1, 0xF, 0xF, true));
    } else if constexpr (M == 2) { // quad_perm [2,3,0,1]
        return __uint_as_float((unsigned)__builtin_amdgcn_update_dpp(0, (int)u, 0x4E, 0xF, 0xF, true));
    } else if constexpr (M == 4) { // ds_swizzle BitMode xor=4
        return __uint_as_float((unsigned)__builtin_amdgcn_ds_swizzle((int)u, 0x101F));
    } else if constexpr (M == 8) { // row_ror:8 == xor8 within 16
        return __uint_as_float((unsigned)__builtin_amdgcn_update_dpp(0, (int)u, 0x128, 0xF, 0xF, true));
    } else if constexpr (M == 16) {
#if __has_builtin(__builtin_amdgcn_permlane16_swap)
        auto r = __builtin_amdgcn_permlane16_swap(u, u, false, false);
        return __uint_as_float((lane & 16) ? r[0] : r[1]);
#else
        return __uint_as_float((unsigned)__builtin_amdgcn_ds_swizzle((int)u, 0x401F));
#endif
    } else {
#if __has_builtin(__builtin_amdgcn_permlane32_swap)
        auto r = __builtin_amdgcn_permlane32_swap(u, u, false, false);
        return __uint_as_float((lane & 32) ? r[0] : r[1]);
#else
        return __shfl_xor(v, 32, 64);
#endif
    }
}

// U = Rz(tz) @ Ry(ty) @ Rx(tx)  (SU(2): u11 = conj(u00), u10 = -conj(u01))
__device__ __forceinline__ void make_u(float tx, float ty, float tz,
                                       float& u00r, float& u00i, float& u01r, float& u01i,
                                       float& u10r, float& u10i, float& u11r, float& u11i) {
    float cx, sx, cy, sy, cz, sz;
    __sincosf(0.5f * tx, &sx, &cx);
    __sincosf(0.5f * ty, &sy, &cy);
    __sincosf(0.5f * tz, &sz, &cz);
    u00r =  cz * cy * cx + sz * sy * sx;
    u00i =  cz * sy * sx - sz * cy * cx;
    u01r = -cz * sy * cx - sz * cy * sx;
    u01i =  sz * sy * cx - cz * cy * sx;
    u10r = -u01r;  u10i =  u01i;
    u11r =  u00r;  u11i = -u00i;
}

// Setup: 60 gate matrices (6 layers x 10 qubits), batch-independent.
// gm[g*16 + 0..7]  = V0 = U ; gm[g*16 + 8..15] = V1 = -i*U*X  (fusion W = c*V0 + s*V1)
__global__ void pqc_setup(const float* __restrict__ theta, float* __restrict__ gm) {
    int g = threadIdx.x;
    if (g >= (NL + 1) * NQ) return;
    const float* th = theta + g * 3;
    float u00r, u00i, u01r, u01i, u10r, u10i, u11r, u11i;
    make_u(th[0], th[1], th[2], u00r, u00i, u01r, u01i, u10r, u10i, u11r, u11i);
    float* o = gm + g * 16;
    o[0] = u00r;  o[1] = u00i;  o[2] = u01r;  o[3] = u01i;
    o[4] = u10r;  o[5] = u10i;  o[6] = u11r;  o[7] = u11i;
    o[8]  = u01i; o[9]  = -u01r; o[10] = u00i; o[11] = -u00r;
    o[12] = u11i; o[13] = -u11r; o[14] = u10i; o[15] = -u10r;
}

// State: amplitude k = lane*16 + r, r = 2*j + h.  fr[j]/fi[j] hold re/im of (r=2j, r=2j+1).
template <int P>
__device__ __forceinline__ void apply_p(v2f fr[8], v2f fi[8],
                                        float w00r, float w00i, float w01r, float w01i,
                                        float w10r, float w10i, float w11r, float w11i,
                                        int lane) {
    if constexpr (P == 0) {
        v2f c0r = { w00r, w11r }, c0i = { w00i, w11i };
        v2f c1r = { w01r, w10r }, c1i = { w01i, w10i };
#pragma unroll
        for (int j = 0; j < 8; ++j) {
            v2f ar = fr[j], ai = fi[j];
            v2f srp = ar.yx, sip = ai.yx;
            fr[j] = c0r * ar - c0i * ai + c1r * srp - c1i * sip;
            fi[j] = c0r * ai + c0i * ar + c1r * sip + c1i * srp;
        }
    } else if constexpr (P < 4) {
        constexpr int LJ = 1 << (P - 1);
        v2f a00r = sp(w00r), a00i = sp(w00i), a01r = sp(w01r), a01i = sp(w01i);
        v2f a10r = sp(w10r), a10i = sp(w10i), a11r = sp(w11r), a11i = sp(w11i);
#pragma unroll
        for (int base = 0; base < 8; ++base) {
            if (base & LJ) continue;
            v2f a0r = fr[base], a0i = fi[base];
            v2f a1r = fr[base | LJ], a1i = fi[base | LJ];
            fr[base]      = a00r * a0r - a00i * a0i + a01r * a1r - a01i * a1i;
            fi[base]      = a00r * a0i + a00i * a0r + a01r * a1i + a01i * a1r;
            fr[base | LJ] = a10r * a0r - a10i * a0i + a11r * a1r - a11i * a1i;
            fi[base | LJ] = a10r * a0i + a10i * a0r + a11r * a1i + a11i * a1r;
        }
    } else {
        constexpr int M = 1 << (P - 4);
        const int bit = (lane >> (P - 4)) & 1;
        v2f pr = sp(bit ? w11r : w00r), pi = sp(bit ? w11i : w00i);
        v2f qr = sp(bit ? w10r : w01r), qi = sp(bit ? w10i : w01i);
#pragma unroll
        for (int j = 0; j < 8; ++j) {
            v2f ofr, ofi;
            ofr.x = lane_xor<M>(fr[j].x, lane);
            ofr.y = lane_xor<M>(fr[j].y, lane);
            ofi.x = lane_xor<M>(fi[j].x, lane);
            ofi.y = lane_xor<M>(fi[j].y, lane);
            v2f nr = pr * fr[j] - pi * fi[j] + qr * ofr - qi * ofi;
            v2f ni = pr * fi[j] + pi * fr[j] + qr * ofi + qi * ofr;
            fr[j] = nr;
            fi[j] = ni;
        }
    }
}

// wire q (PennyLane: wire 0 = MSB) -> bit position 9-q
__device__ __forceinline__ void apply_q(v2f fr[8], v2f fi[8],
                                        float w00r, float w00i, float w01r, float w01i,
                                        float w10r, float w10i, float w11r, float w11i,
                                        int q, int lane) {
    switch (q) {
        case 0: apply_p<9>(fr, fi, w00r, w00i, w01r, w01i, w10r, w10i, w11r, w11i, lane); break;
        case 1: apply_p<8>(fr, fi, w00r, w00i, w01r, w01i, w10r, w10i, w11r, w11i, lane); break;
        case 2: apply_p<7>(fr, fi, w00r, w00i, w01r, w01i, w10r, w10i, w11r, w11i, lane); break;
        case 3: apply_p<6>(fr, fi, w00r, w00i, w01r, w01i, w10r, w10i, w11r, w11i, lane); break;
        case 4: apply_p<5>(fr, fi, w00r, w00i, w01r, w01i, w10r, w10i, w11r, w11i, lane); break;
        case 5: apply_p<4>(fr, fi, w00r, w00i, w01r, w01i, w10r, w10i, w11r, w11i, lane); break;
        case 6: apply_p<3>(fr, fi, w00r, w00i, w01r, w01i, w10r, w10i, w11r, w11i, lane); break;
        case 7: apply_p<2>(fr, fi, w00r, w00i, w01r, w01i, w10r, w10i, w11r, w11i, lane); break;
        case 8: apply_p<1>(fr, fi, w00r, w00i, w01r, w01i, w10r, w10i, w11r, w11i, lane); break;
        case 9: apply_p<0>(fr, fi, w00r, w00i, w01r, w01i, w10r, w10i, w11r, w11i, lane); break;
    }
}

__global__ void __launch_bounds__(256) pqc_kernel(const float* __restrict__ x,
                                                  const float* __restrict__ lam,
                                                  const float* __restrict__ w,
                                                  const float* __restrict__ gm,
                                                  float* __restrict__ out, int B) {
    const int lane = threadIdx.x & 63;
    const int b = blockIdx.x * (blockDim.x >> 6) + (threadIdx.x >> 6);
    if (b >= B) return;
    const int bu = __builtin_amdgcn_readfirstlane(b);

    v2f fr[8], fi[8];
#pragma unroll
    for (int j = 0; j < 8; ++j) { fr[j] = sp(0.f); fi[j] = sp(0.f); }
    if (lane == 0) fr[0].x = 1.f;

    // CZ-ring and Z^n sign vectors (+-1 per amplitude).
    v2f sv[8];
    unsigned zmask = 0;
#pragma unroll
    for (int j = 0; j < 8; ++j) {
#pragma unroll
        for (int h = 0; h < 2; ++h) {
            int k = (lane << 4) | (2 * j + h);
            int par = (__popc(k & (k >> 1)) + ((k & (k >> 9)) & 1)) & 1;
            float s = __uint_as_float(0x3f800000u | ((unsigned)par << 31));
            if (h == 0) sv[j].x = s; else sv[j].y = s;
            zmask |= (unsigned)(__popc(k) & 1) << (2 * j + h);
        }
    }

    float xr[NQ];
#pragma unroll
    for (int q = 0; q < NQ; ++q) xr[q] = x[bu * NQ + q];

    // Layer 0: variational gates straight from precomputed V0.
#pragma unroll
    for (int q = 0; q < NQ; ++q) {
        const float* g = gm + q * 16;
        apply_q(fr, fi, g[0], g[1], g[2], g[3], g[4], g[5], g[6], g[7], q, lane);
    }
#pragma unroll
    for (int j = 0; j < 8; ++j) { fr[j] *= sv[j]; fi[j] *= sv[j]; }

    // Layers 1..NL: W = c*V0 + s*V1 (fused U_theta(l) * RX(x*lam(l-1))), then CZ ring.
#pragma unroll
    for (int l = 1; l <= NL; ++l) {
        const float* lm = lam + (l - 1) * NQ;
#pragma unroll
        for (int q = 0; q < NQ; ++q) {
            const float* g = gm + (l * NQ + q) * 16;
            float t = xr[q] * lm[q];
            float c, s;
            __sincosf(0.5f * t, &s, &c);
            float w00r = c * g[0] + s * g[8],  w00i = c * g[1] + s * g[9];
            float w01r = c * g[2] + s * g[10], w01i = c * g[3] + s * g[11];
            float w10r = c * g[4] + s * g[12], w10i = c * g[5] + s * g[13];
            float w11r = c * g[6] + s * g[14], w11i = c * g[7] + s * g[15];
            apply_q(fr, fi, w00r, w00i, w01r, w01i, w10r, w10i, w11r, w11i, q, lane);
        }
#pragma unroll
        for (int j = 0; j < 8; ++j) { fr[j] *= sv[j]; fi[j] *= sv[j]; }
    }

    // <Z^n> = sum |amp|^2 * (-1)^popcount(k)
    v2f acc = sp(0.f);
#pragma unroll
    for (int j = 0; j < 8; ++j) {
        v2f zs;
        zs.x = __uint_as_float(0x3f800000u | (((zmask >> (2 * j)) & 1u) << 31));
        zs.y = __uint_as_float(0x3f800000u | (((zmask >> (2 * j + 1)) & 1u) << 31));
        acc += zs * (fr[j] * fr[j] + fi[j] * fi[j]);
    }
    float ez = acc.x + acc.y;
#pragma unroll
    for (int off = 32; off > 0; off >>= 1) ez += __shfl_xor(ez, off, 64);

    if (lane == 0) {
        float l0 = ez * w[0], l1 = ez * w[1];   // BETA = 1
        float m = fmaxf(l0, l1);
        float e0 = __expf(l0 - m), e1 = __expf(l1 - m);
        float inv = 1.f / (e0 + e1);
        out[2 * b + 0] = e0 * inv;
        out[2 * b + 1] = e1 * inv;
    }
}

extern "C" void kernel_launch(void* const* d_in, const int* in_sizes, int n_in,
                              void* d_out, int out_size, void* d_ws, size_t ws_size,
                              hipStream_t stream) {
    const float* x     = (const float*)d_in[0];
    const float* theta = (const float*)d_in[1];
    const float* lam   = (const float*)d_in[2];
    const float* w     = (const float*)d_in[3];
    float* out = (float*)d_out;
    float* gm  = (float*)d_ws;                 // 60 gates * 16 floats = 3840 B

    const int B = in_sizes[0] / NQ;            // 2048
    hipLaunchKernelGGL(pqc_setup, dim3(1), dim3(64), 0, stream, theta, gm);

    const int wavesPerBlock = 256 / 64;        // 4
    const int blocks = (B + wavesPerBlock - 1) / wavesPerBlock;
    hipLaunchKernelGGL(pqc_kernel, dim3(blocks), dim3(256), 0, stream,
                       x, lam, w, gm, out, B);
}